// Round 17
// baseline (1400.455 us; speedup 1.0000x reference)
//
#include <hip/hip_runtime.h>

#define HH 128
#define WW 128

typedef __bf16 bf16;
typedef bf16 bf16x8 __attribute__((ext_vector_type(8)));
typedef float f32x4 __attribute__((ext_vector_type(4)));

__device__ __forceinline__ float hsig(float x) {
    return fminf(fmaxf(fmaf(0.2f, x, 0.5f), 0.f), 1.f);
}
__device__ __forceinline__ float ftanh(float x) {
    const float u = __expf(2.f * fminf(x, 40.f));
    return (u - 1.f) * __builtin_amdgcn_rcpf(u + 1.f);
}
__device__ __forceinline__ bf16x8 zero8() {
    bf16x8 z;
    #pragma unroll
    for (int j = 0; j < 8; ++j) z[j] = (bf16)0.f;
    return z;
}

// ---- one-time weight prep: fp32 [tap][ci][cout] -> bf16 Wt[l][tap][cout][ci64]
// Unified ci64 layout: input cins [0,CX) (CX=16 for l0, else 32), zeros [CX,32),
// own-h cins [32,64).
__global__ void prep_weights(const float* __restrict__ Wx0, const float* __restrict__ Wh0,
                             const float* __restrict__ Wx1, const float* __restrict__ Wh1,
                             const float* __restrict__ Wx2, const float* __restrict__ Wh2,
                             const float* __restrict__ Wx3, const float* __restrict__ Wh3,
                             bf16* __restrict__ Wt)
{
    int idx = blockIdx.x * 256 + threadIdx.x;      // 4*9*128*64 = 294912
    if (idx >= 4 * 9 * 128 * 64) return;
    const int l = idx / 73728;
    int r = idx - l * 73728;
    const int tap = r / (128 * 64);
    r -= tap * 128 * 64;
    const int co = r >> 6;
    const int ci = r & 63;
    const int CX = (l == 0) ? 16 : 32;
    const float* Wx = (l == 0) ? Wx0 : (l == 1) ? Wx1 : (l == 2) ? Wx2 : Wx3;
    const float* Wh = (l == 0) ? Wh0 : (l == 1) ? Wh1 : (l == 2) ? Wh2 : Wh3;
    float v = 0.f;
    if (ci < 32) { if (ci < CX) v = Wx[((size_t)tap * CX + ci) * 128 + co]; }
    else          v = Wh[((size_t)tap * 32 + (ci - 32)) * 128 + co];
    Wt[(size_t)l * 73728 + ((size_t)tap * 128 + co) * 64 + ci] = (bf16)v;
}

constexpr int ST = 72;   // ci stride (elems) in LDS halo

// Diagonal-wavefront ConvLSTM stage kernel. R16 structure, but staging is
// split 4+3 (register arrays reused) to cut peak VGPR live-set 56->32, and
// launch_bounds targets 3 waves/EU (total regs <=~160/wave -> 12 waves/CU).
__global__ __launch_bounds__(128, 3)
void lstm_stage(const float* __restrict__ x,
                const bf16* __restrict__ Wt,
                const float* __restrict__ b0, const float* __restrict__ b1,
                const float* __restrict__ b2, const float* __restrict__ b3,
                bf16* __restrict__ h0, bf16* __restrict__ h1,
                bf16* __restrict__ h2, bf16* __restrict__ h3,
                float* __restrict__ cbase,
                float* __restrict__ outf,
                const int d, const int lmin)
{
    __shared__ bf16 sact[108 * ST];        // halo 6y x 18x pixels, 64 ci each

    const int tid = threadIdx.x;
    const int bx = blockIdx.x, by = blockIdx.y;
    const int s  = blockIdx.z >> 2, bb = blockIdx.z & 3;
    const int l  = lmin + s;
    const int t  = d - l;

    const size_t S = (size_t)4 * HH * WW * 32;
    bf16* hlbase = (l == 0) ? h0 : (l == 1) ? h1 : (l == 2) ? h2 : h3;
    bf16*       hcur = hlbase + (size_t)((l == 0) ? (t & 3) : (t & 1)) * S;
    const bf16* hprv = hlbase + (size_t)((l == 0) ? ((t + 3) & 3) : ((t + 1) & 1)) * S;
    const bf16* hin  = (l == 1) ? h0 + (size_t)(t & 3) * S
                     : (l == 2) ? h1 + (size_t)(t & 1) * S
                     : (l == 3) ? h2 + (size_t)(t & 1) * S : nullptr;
    const bf16* resp = h0 + (size_t)(t & 3) * S;           // layer0 h at t (l==3)
    const float* bias = (l == 0) ? b0 : (l == 1) ? b1 : (l == 2) ? b2 : b3;
    float* cst = cbase + (size_t)l * S;

    const int lane = tid & 63;
    const int p    = tid >> 6;        // wave parity: nb = p + 2q
    const int col  = lane & 15;       // A row (x) / C col / B col
    const int krow = lane >> 4;       // k-slice / C row block
    const int abase = col * ST + krow * 8;
    const int x0 = bx * 16 + krow * 4;
    const int f  = p * 16 + col;

    // ---- EARLY: c prefetch (latency hides under staging + MFMA) ----
    const size_t pb0 = (((size_t)bb * HH + by * 4) * WW + x0) * 32 + f;
    float cpre[16];
    #pragma unroll
    for (int i = 0; i < 16; ++i) cpre[i] = 0.f;
    if (t > 0) {
        #pragma unroll
        for (int mt = 0; mt < 4; ++mt)
            #pragma unroll
            for (int j = 0; j < 4; ++j)
                cpre[mt * 4 + j] = cst[pb0 + (size_t)(mt * WW + j) * 32];
    }

    const bf16* __restrict__ wb0 = Wt + (size_t)l * 73728 + (size_t)(p * 16 + col) * 64 + krow * 8;

    bf16x8 A0[4][2], A1[4][2], B0[2][4], B1[2][4];

#define LOAD_B(Bbuf, tap) do {                                               \
        const bf16* wt_ = wb0 + (size_t)(tap) * 8192;                        \
        _Pragma("unroll")                                                    \
        for (int q_ = 0; q_ < 4; ++q_) {                                     \
            Bbuf[0][q_] = *(const bf16x8*)(wt_ + q_ * 2048);                 \
            Bbuf[1][q_] = *(const bf16x8*)(wt_ + q_ * 2048 + 32);            \
        }                                                                    \
    } while (0)

    // ---- EARLY: tap-0 weights in flight before staging ----
    LOAD_B(B0, 0);

    // ---- staging: two half-batches (4 then 3), register arrays reused.
    //      UNION: rh = h-halo (l>0) OR raw bits of x[0..3] (l==0, fp32);
    //             rr = residual OR raw bits of x[4..7].
    auto load_item = [&](int k, bf16x8& RH, bf16x8& RR) {
        RH = zero8(); RR = zero8();
        const int i = tid + k * 128;
        if (i < 108 * 8) {
            const int pix = i >> 3, g = i & 7;
            const int hy = pix / 18, hx = pix - hy * 18;
            const int sy = by * 4 - 1 + hy, sx = bx * 16 - 1 + hx;
            if (((unsigned)sy < HH) && ((unsigned)sx < WW)) {
                const size_t poff = (size_t)sy * WW + sx;
                if (g < 4) {
                    if (l == 0) {
                        if (g < 2) {               // raw-bit load of 8 fp32
                            const float* xp = x + ((size_t)(bb * 8 + t) * HH * WW + poff) * 16 + g * 8;
                            RH = *(const bf16x8*)xp;        // x[0..3] bits
                            RR = *(const bf16x8*)(xp + 4);  // x[4..7] bits
                        }
                    } else {
                        RH = *(const bf16x8*)(hin + ((size_t)bb * HH * WW + poff) * 32 + g * 8);
                        if (l == 3)
                            RR = *(const bf16x8*)(resp + ((size_t)bb * HH * WW + poff) * 32 + g * 8);
                    }
                } else if (t > 0) {
                    RH = *(const bf16x8*)(hprv + ((size_t)bb * HH * WW + poff) * 32 + (g - 4) * 8);
                }
            }
        }
    };
    auto store_item = [&](int k, const bf16x8& RH, const bf16x8& RR) {
        const int i = tid + k * 128;
        if (i < 108 * 8) {
            const int pix = i >> 3, g = i & 7;
            bf16x8 w;
            if (g < 4 && l == 0) {
                if (g < 2) {                      // bit-cast back, convert to bf16
                    const f32x4 a = __builtin_bit_cast(f32x4, RH);
                    const f32x4 b = __builtin_bit_cast(f32x4, RR);
                    w[0] = (bf16)a.x; w[1] = (bf16)a.y; w[2] = (bf16)a.z; w[3] = (bf16)a.w;
                    w[4] = (bf16)b.x; w[5] = (bf16)b.y; w[6] = (bf16)b.z; w[7] = (bf16)b.w;
                } else {
                    w = RH;                       // zero pad (stayed zero)
                }
            } else if (g < 4 && l == 3) {         // residual add + relu
                #pragma unroll
                for (int j = 0; j < 8; ++j)
                    w[j] = (bf16)fmaxf((float)RH[j] + (float)RR[j], 0.f);
            } else if (g < 4 && l == 2) {         // relu only
                #pragma unroll
                for (int j = 0; j < 8; ++j)
                    w[j] = (bf16)fmaxf((float)RH[j], 0.f);
            } else {
                w = RH;                           // pure copy (h-part, or l==1 input)
            }
            *(bf16x8*)(&sact[pix * ST + g * 8]) = w;
        }
    };

    bf16x8 rh[4], rr[4];
    #pragma unroll
    for (int k = 0; k < 4; ++k) load_item(k, rh[k], rr[k]);
    #pragma unroll
    for (int k = 0; k < 4; ++k) store_item(k, rh[k], rr[k]);
    #pragma unroll
    for (int k = 4; k < 7; ++k) load_item(k, rh[k - 4], rr[k - 4]);
    #pragma unroll
    for (int k = 4; k < 7; ++k) store_item(k, rh[k - 4], rr[k - 4]);
    __syncthreads();

    f32x4 acc2[4][4];                 // [mt = row][q = gate]
    #pragma unroll
    for (int q = 0; q < 4; ++q) {
        const float bv = bias[(p + 2 * q) * 16 + col];
        #pragma unroll
        for (int mt = 0; mt < 4; ++mt) acc2[mt][q] = (f32x4){bv, bv, bv, bv};
    }

#define LOAD_A(Abuf, tap) do {                                               \
        const int dy_ = (tap) / 3, dx_ = (tap) - dy_ * 3;                    \
        const int o_ = abase + (dy_ * 18 + dx_) * ST;                        \
        _Pragma("unroll")                                                    \
        for (int mt_ = 0; mt_ < 4; ++mt_) {                                  \
            Abuf[mt_][0] = *(const bf16x8*)(&sact[o_ + mt_ * 18 * ST]);       \
            Abuf[mt_][1] = *(const bf16x8*)(&sact[o_ + mt_ * 18 * ST + 32]);  \
        }                                                                    \
    } while (0)

#define MFMA_TAP(Abuf, Bbuf) do {                                            \
        __builtin_amdgcn_s_setprio(1);                                       \
        _Pragma("unroll")                                                    \
        for (int kb_ = 0; kb_ < 2; ++kb_)                                    \
            _Pragma("unroll")                                                \
            for (int mt_ = 0; mt_ < 4; ++mt_)                                \
                _Pragma("unroll")                                            \
                for (int q_ = 0; q_ < 4; ++q_)                               \
                    acc2[mt_][q_] = __builtin_amdgcn_mfma_f32_16x16x32_bf16( \
                        Abuf[mt_][kb_], Bbuf[kb_][q_], acc2[mt_][q_], 0, 0, 0); \
        __builtin_amdgcn_s_setprio(0);                                       \
    } while (0)

    LOAD_A(A0, 0);
    #pragma unroll 1
    for (int k = 0; k < 4; ++k) {
        const int t1 = 2 * k + 1, t2 = 2 * k + 2;
        LOAD_A(A1, t1); LOAD_B(B1, t1);
        MFMA_TAP(A0, B0);
        LOAD_A(A0, t2); LOAD_B(B0, t2);
        MFMA_TAP(A1, B1);
    }
    MFMA_TAP(A0, B0);   // tap 8

#undef LOAD_A
#undef LOAD_B
#undef MFMA_TAP

    // ---- lane-local LSTM pointwise; c_old from prefetched registers ----
    #pragma unroll
    for (int mt = 0; mt < 4; ++mt) {
        #pragma unroll
        for (int j = 0; j < 4; ++j) {
            const size_t pb = pb0 + (size_t)(mt * WW + j) * 32;
            const float zi = acc2[mt][0][j];
            const float zf = acc2[mt][1][j];
            const float zg = acc2[mt][2][j];
            const float zo = acc2[mt][3][j];
            const float ig = hsig(zi), fg = hsig(zf);
            const float gg = ftanh(zg), og = hsig(zo);
            const float cn = fmaf(fg, cpre[mt * 4 + j], ig * gg);
            const float hn = og * ftanh(cn);
            if (t != 7) cst[pb] = cn;                 // c(8) never read
            if (l == 3 && t == 7) outf[pb] = hn;
            else                  hcur[pb] = (bf16)hn;
        }
    }
}

extern "C" void kernel_launch(void* const* d_in, const int* in_sizes, int n_in,
                              void* d_out, int out_size, void* d_ws, size_t ws_size,
                              hipStream_t stream) {
    const float* x = (const float*)d_in[0];
    const float* Wx[4] = {(const float*)d_in[1], (const float*)d_in[4],
                          (const float*)d_in[7], (const float*)d_in[10]};
    const float* Wh[4] = {(const float*)d_in[2], (const float*)d_in[5],
                          (const float*)d_in[8], (const float*)d_in[11]};
    const float* bs[4] = {(const float*)d_in[3], (const float*)d_in[6],
                          (const float*)d_in[9], (const float*)d_in[12]};
    float* out = (float*)d_out;

    const size_t S  = (size_t)4 * HH * WW * 32;   // one [B,H,W,32] buffer (elements)
    const size_t WT = (size_t)4 * 73728;          // transposed weights (bf16 elems)

    bf16* wt = (bf16*)d_ws;
    bf16* h0 = wt + WT;              // layer0: 4-deep ring (residual read at d+3)
    bf16* h1 = h0 + 4 * S;           // layers 1..3: 2-deep rings
    bf16* h2 = h1 + 2 * S;
    bf16* h3 = h2 + 2 * S;
    float* cb = (float*)(h3 + 2 * S);   // 4 x S fp32 c-state

    prep_weights<<<1152, 256, 0, stream>>>(Wx[0], Wh[0], Wx[1], Wh[1],
                                           Wx[2], Wh[2], Wx[3], Wh[3], wt);

    // Diagonal wavefront: d = t + l, stages (t, l) on one diagonal are independent.
    for (int d = 0; d <= 10; ++d) {
        const int lmin = (d > 7) ? (d - 7) : 0;
        const int lmax = (d < 3) ? d : 3;
        const int nst  = lmax - lmin + 1;
        dim3 grid(WW / 16, HH / 4, nst * 4);
        lstm_stage<<<grid, dim3(128), 0, stream>>>(
            x, wt, bs[0], bs[1], bs[2], bs[3],
            h0, h1, h2, h3, cb, out, d, lmin);
    }
}

// Round 18
// 580.689 us; speedup vs baseline: 2.4117x; 2.4117x over previous
//
#include <hip/hip_runtime.h>

#define HH 128
#define WW 128

typedef __bf16 bf16;
typedef bf16 bf16x8 __attribute__((ext_vector_type(8)));
typedef float f32x4 __attribute__((ext_vector_type(4)));

__device__ __forceinline__ float hsig(float x) {
    return fminf(fmaxf(fmaf(0.2f, x, 0.5f), 0.f), 1.f);
}
__device__ __forceinline__ float ftanh(float x) {
    const float u = __expf(2.f * fminf(x, 40.f));
    return (u - 1.f) * __builtin_amdgcn_rcpf(u + 1.f);
}
__device__ __forceinline__ bf16x8 zero8() {
    bf16x8 z;
    #pragma unroll
    for (int j = 0; j < 8; ++j) z[j] = (bf16)0.f;
    return z;
}

// ---- one-time weight prep: fp32 [tap][ci][cout] -> bf16 Wt[l][tap][cout][ci64]
// Unified ci64 layout: input cins [0,CX) (CX=16 for l0, else 32), zeros [CX,32),
// own-h cins [32,64).
__global__ void prep_weights(const float* __restrict__ Wx0, const float* __restrict__ Wh0,
                             const float* __restrict__ Wx1, const float* __restrict__ Wh1,
                             const float* __restrict__ Wx2, const float* __restrict__ Wh2,
                             const float* __restrict__ Wx3, const float* __restrict__ Wh3,
                             bf16* __restrict__ Wt)
{
    int idx = blockIdx.x * 256 + threadIdx.x;      // 4*9*128*64 = 294912
    if (idx >= 4 * 9 * 128 * 64) return;
    const int l = idx / 73728;
    int r = idx - l * 73728;
    const int tap = r / (128 * 64);
    r -= tap * 128 * 64;
    const int co = r >> 6;
    const int ci = r & 63;
    const int CX = (l == 0) ? 16 : 32;
    const float* Wx = (l == 0) ? Wx0 : (l == 1) ? Wx1 : (l == 2) ? Wx2 : Wx3;
    const float* Wh = (l == 0) ? Wh0 : (l == 1) ? Wh1 : (l == 2) ? Wh2 : Wh3;
    float v = 0.f;
    if (ci < 32) { if (ci < CX) v = Wx[((size_t)tap * CX + ci) * 128 + co]; }
    else          v = Wh[((size_t)tap * 32 + (ci - 32)) * 128 + co];
    Wt[(size_t)l * 73728 + ((size_t)tap * 128 + co) * 64 + ci] = (bf16)v;
}

constexpr int ST = 72;   // ci stride (elems) in LDS halo

// Diagonal-wavefront ConvLSTM stage kernel, M=128/wave: tile 16(w) x 8(h),
// 2 waves (parity split on couts), each wave computes all 8 row-tiles
// (acc[8][4], 128 AGPR). Per tap: 16 A ds_reads + 16 B loads + 64 MFMA (8:1).
// Blocks/stage = 512 -> 2 occupancy rounds mid-diagonal (was 4).
// Staging 6+6 split; cpre 16+16 split; B dbuf; A streamed per-mt.
__global__ __launch_bounds__(128, 2)
void lstm_stage(const float* __restrict__ x,
                const bf16* __restrict__ Wt,
                const float* __restrict__ b0, const float* __restrict__ b1,
                const float* __restrict__ b2, const float* __restrict__ b3,
                bf16* __restrict__ h0, bf16* __restrict__ h1,
                bf16* __restrict__ h2, bf16* __restrict__ h3,
                float* __restrict__ cbase,
                float* __restrict__ outf,
                const int d, const int lmin)
{
    __shared__ bf16 sact[180 * ST];        // halo 10y x 18x pixels, 64 ci each

    const int tid = threadIdx.x;
    const int bx = blockIdx.x, by = blockIdx.y;
    const int s  = blockIdx.z >> 2, bb = blockIdx.z & 3;
    const int l  = lmin + s;
    const int t  = d - l;

    const size_t S = (size_t)4 * HH * WW * 32;
    bf16* hlbase = (l == 0) ? h0 : (l == 1) ? h1 : (l == 2) ? h2 : h3;
    bf16*       hcur = hlbase + (size_t)((l == 0) ? (t & 3) : (t & 1)) * S;
    const bf16* hprv = hlbase + (size_t)((l == 0) ? ((t + 3) & 3) : ((t + 1) & 1)) * S;
    const bf16* hin  = (l == 1) ? h0 + (size_t)(t & 3) * S
                     : (l == 2) ? h1 + (size_t)(t & 1) * S
                     : (l == 3) ? h2 + (size_t)(t & 1) * S : nullptr;
    const bf16* resp = h0 + (size_t)(t & 3) * S;           // layer0 h at t (l==3)
    const float* bias = (l == 0) ? b0 : (l == 1) ? b1 : (l == 2) ? b2 : b3;
    float* cst = cbase + (size_t)l * S;

    const int lane = tid & 63;
    const int p    = tid >> 6;        // wave parity: nb = p + 2q
    const int col  = lane & 15;       // A row (x) / C col / B col
    const int krow = lane >> 4;       // k-slice / C row block
    const int abase = col * ST + krow * 8;
    const int x0 = bx * 16 + krow * 4;
    const int f  = p * 16 + col;

    const size_t pb0 = (((size_t)bb * HH + by * 8) * WW + x0) * 32 + f;
    const bf16* __restrict__ wb0 = Wt + (size_t)l * 73728 + (size_t)(p * 16 + col) * 64 + krow * 8;

    bf16x8 B0[2][4], B1[2][4];

#define LOAD_B(Bbuf, tap) do {                                               \
        const bf16* wt_ = wb0 + (size_t)(tap) * 8192;                        \
        _Pragma("unroll")                                                    \
        for (int q_ = 0; q_ < 4; ++q_) {                                     \
            Bbuf[0][q_] = *(const bf16x8*)(wt_ + q_ * 2048);                 \
            Bbuf[1][q_] = *(const bf16x8*)(wt_ + q_ * 2048 + 32);            \
        }                                                                    \
    } while (0)

    // ---- EARLY: tap-0 weights + first half of c prefetch in flight ----
    LOAD_B(B0, 0);
    float cpre[32];
    #pragma unroll
    for (int i = 0; i < 32; ++i) cpre[i] = 0.f;
    if (t > 0) {
        #pragma unroll
        for (int mt = 0; mt < 4; ++mt)
            #pragma unroll
            for (int j = 0; j < 4; ++j)
                cpre[mt * 4 + j] = cst[pb0 + (size_t)(mt * WW + j) * 32];
    }

    // ---- staging: two half-batches of 6 (1440 items / 128 thr = 11.25) ----
    auto load_item = [&](int k, bf16x8& RH, bf16x8& RR) {
        RH = zero8(); RR = zero8();
        const int i = tid + k * 128;
        if (i < 180 * 8) {
            const int pix = i >> 3, g = i & 7;
            const int hy = pix / 18, hx = pix - hy * 18;
            const int sy = by * 8 - 1 + hy, sx = bx * 16 - 1 + hx;
            if (((unsigned)sy < HH) && ((unsigned)sx < WW)) {
                const size_t poff = (size_t)sy * WW + sx;
                if (g < 4) {
                    if (l == 0) {
                        if (g < 2) {               // raw-bit load of 8 fp32
                            const float* xp = x + ((size_t)(bb * 8 + t) * HH * WW + poff) * 16 + g * 8;
                            RH = *(const bf16x8*)xp;        // x[0..3] bits
                            RR = *(const bf16x8*)(xp + 4);  // x[4..7] bits
                        }
                    } else {
                        RH = *(const bf16x8*)(hin + ((size_t)bb * HH * WW + poff) * 32 + g * 8);
                        if (l == 3)
                            RR = *(const bf16x8*)(resp + ((size_t)bb * HH * WW + poff) * 32 + g * 8);
                    }
                } else if (t > 0) {
                    RH = *(const bf16x8*)(hprv + ((size_t)bb * HH * WW + poff) * 32 + (g - 4) * 8);
                }
            }
        }
    };
    auto store_item = [&](int k, const bf16x8& RH, const bf16x8& RR) {
        const int i = tid + k * 128;
        if (i < 180 * 8) {
            const int pix = i >> 3, g = i & 7;
            bf16x8 w;
            if (g < 4 && l == 0) {
                if (g < 2) {                      // bit-cast back, convert to bf16
                    const f32x4 a = __builtin_bit_cast(f32x4, RH);
                    const f32x4 b = __builtin_bit_cast(f32x4, RR);
                    w[0] = (bf16)a.x; w[1] = (bf16)a.y; w[2] = (bf16)a.z; w[3] = (bf16)a.w;
                    w[4] = (bf16)b.x; w[5] = (bf16)b.y; w[6] = (bf16)b.z; w[7] = (bf16)b.w;
                } else {
                    w = RH;                       // zero pad
                }
            } else if (g < 4 && l == 3) {         // residual add + relu
                #pragma unroll
                for (int j = 0; j < 8; ++j)
                    w[j] = (bf16)fmaxf((float)RH[j] + (float)RR[j], 0.f);
            } else if (g < 4 && l == 2) {         // relu only
                #pragma unroll
                for (int j = 0; j < 8; ++j)
                    w[j] = (bf16)fmaxf((float)RH[j], 0.f);
            } else {
                w = RH;                           // pure copy
            }
            *(bf16x8*)(&sact[pix * ST + g * 8]) = w;
        }
    };

    {
        bf16x8 rh[6], rr[6];
        #pragma unroll
        for (int k = 0; k < 6; ++k) load_item(k, rh[k], rr[k]);
        #pragma unroll
        for (int k = 0; k < 6; ++k) store_item(k, rh[k], rr[k]);
        #pragma unroll
        for (int k = 6; k < 12; ++k) load_item(k, rh[k - 6], rr[k - 6]);
        #pragma unroll
        for (int k = 6; k < 12; ++k) store_item(k, rh[k - 6], rr[k - 6]);
    }
    // ---- second half of c prefetch (completes during tap loop) ----
    if (t > 0) {
        #pragma unroll
        for (int mt = 4; mt < 8; ++mt)
            #pragma unroll
            for (int j = 0; j < 4; ++j)
                cpre[mt * 4 + j] = cst[pb0 + (size_t)(mt * WW + j) * 32];
    }
    __syncthreads();

    f32x4 acc2[8][4];                 // [mt = row-tile][q = gate]
    #pragma unroll
    for (int q = 0; q < 4; ++q) {
        const float bv = bias[(p + 2 * q) * 16 + col];
        #pragma unroll
        for (int mt = 0; mt < 8; ++mt) acc2[mt][q] = (f32x4){bv, bv, bv, bv};
    }

    // per tap: stream A per-mt (8 V live), MFMA against resident B buffer
#define MFMA_TAP(Bbuf, tap) do {                                             \
        const int dy_ = (tap) / 3, dx_ = (tap) - dy_ * 3;                    \
        const int o_ = abase + (dy_ * 18 + dx_) * ST;                        \
        _Pragma("unroll")                                                    \
        for (int mt_ = 0; mt_ < 8; ++mt_) {                                  \
            const bf16x8 Aa = *(const bf16x8*)(&sact[o_ + mt_ * 18 * ST]);    \
            const bf16x8 Ab = *(const bf16x8*)(&sact[o_ + mt_ * 18 * ST + 32]);\
            __builtin_amdgcn_s_setprio(1);                                   \
            _Pragma("unroll")                                                \
            for (int q_ = 0; q_ < 4; ++q_)                                   \
                acc2[mt_][q_] = __builtin_amdgcn_mfma_f32_16x16x32_bf16(     \
                    Aa, Bbuf[0][q_], acc2[mt_][q_], 0, 0, 0);                \
            _Pragma("unroll")                                                \
            for (int q_ = 0; q_ < 4; ++q_)                                   \
                acc2[mt_][q_] = __builtin_amdgcn_mfma_f32_16x16x32_bf16(     \
                    Ab, Bbuf[1][q_], acc2[mt_][q_], 0, 0, 0);                \
            __builtin_amdgcn_s_setprio(0);                                   \
        }                                                                    \
    } while (0)

    #pragma unroll 1
    for (int k = 0; k < 4; ++k) {
        const int t1 = 2 * k + 1, t2 = 2 * k + 2;
        LOAD_B(B1, t1);
        MFMA_TAP(B0, 2 * k);
        LOAD_B(B0, t2);
        MFMA_TAP(B1, t1);
    }
    MFMA_TAP(B0, 8);   // tap 8

#undef LOAD_B
#undef MFMA_TAP

    // ---- lane-local LSTM pointwise; c_old from prefetched registers ----
    #pragma unroll
    for (int mt = 0; mt < 8; ++mt) {
        #pragma unroll
        for (int j = 0; j < 4; ++j) {
            const size_t pb = pb0 + (size_t)(mt * WW + j) * 32;
            const float zi = acc2[mt][0][j];
            const float zf = acc2[mt][1][j];
            const float zg = acc2[mt][2][j];
            const float zo = acc2[mt][3][j];
            const float ig = hsig(zi), fg = hsig(zf);
            const float gg = ftanh(zg), og = hsig(zo);
            const float cn = fmaf(fg, cpre[mt * 4 + j], ig * gg);
            const float hn = og * ftanh(cn);
            if (t != 7) cst[pb] = cn;                 // c(8) never read
            if (l == 3 && t == 7) outf[pb] = hn;
            else                  hcur[pb] = (bf16)hn;
        }
    }
}

extern "C" void kernel_launch(void* const* d_in, const int* in_sizes, int n_in,
                              void* d_out, int out_size, void* d_ws, size_t ws_size,
                              hipStream_t stream) {
    const float* x = (const float*)d_in[0];
    const float* Wx[4] = {(const float*)d_in[1], (const float*)d_in[4],
                          (const float*)d_in[7], (const float*)d_in[10]};
    const float* Wh[4] = {(const float*)d_in[2], (const float*)d_in[5],
                          (const float*)d_in[8], (const float*)d_in[11]};
    const float* bs[4] = {(const float*)d_in[3], (const float*)d_in[6],
                          (const float*)d_in[9], (const float*)d_in[12]};
    float* out = (float*)d_out;

    const size_t S  = (size_t)4 * HH * WW * 32;   // one [B,H,W,32] buffer (elements)
    const size_t WT = (size_t)4 * 73728;          // transposed weights (bf16 elems)

    bf16* wt = (bf16*)d_ws;
    bf16* h0 = wt + WT;              // layer0: 4-deep ring (residual read at d+3)
    bf16* h1 = h0 + 4 * S;           // layers 1..3: 2-deep rings
    bf16* h2 = h1 + 2 * S;
    bf16* h3 = h2 + 2 * S;
    float* cb = (float*)(h3 + 2 * S);   // 4 x S fp32 c-state

    prep_weights<<<1152, 256, 0, stream>>>(Wx[0], Wh[0], Wx[1], Wh[1],
                                           Wx[2], Wh[2], Wx[3], Wh[3], wt);

    // Diagonal wavefront: d = t + l, stages (t, l) on one diagonal are independent.
    for (int d = 0; d <= 10; ++d) {
        const int lmin = (d > 7) ? (d - 7) : 0;
        const int lmax = (d < 3) ? d : 3;
        const int nst  = lmax - lmin + 1;
        dim3 grid(WW / 16, HH / 8, nst * 4);
        lstm_stage<<<grid, dim3(128), 0, stream>>>(
            x, wt, bs[0], bs[1], bs[2], bs[3],
            h0, h1, h2, h3, cb, out, d, lmin);
    }
}